// Round 9
// baseline (245.075 us; speedup 1.0000x reference)
//
#include <hip/hip_runtime.h>
#include <hip/hip_bf16.h>
#include <math.h>

#define BATCH 8192

typedef unsigned short bf16_t;
typedef _Float16 f16_t;
typedef __attribute__((ext_vector_type(2))) _Float16 h2_t;
typedef __attribute__((ext_vector_type(8))) short short8;
typedef __attribute__((ext_vector_type(4))) float f32x4;

union U32H2 { unsigned int u; h2_t h; };

__device__ __forceinline__ float bf2f(bf16_t u) {
    union { unsigned int i; float f; } v; v.i = ((unsigned int)u) << 16; return v.f;
}
__device__ __forceinline__ bf16_t f2bf(float f) {
    union { float f; unsigned int i; } v; v.f = f;
    unsigned int x = v.i;
    unsigned int r = (x + 0x7FFFu + ((x >> 16) & 1u)) >> 16;   // RNE
    return (bf16_t)r;
}
// tanh(x) = sign(x) * (1 - 2/(exp(2|x|)+1)); err ~1e-6
__device__ __forceinline__ float fast_tanh(float x) {
    float ax = fabsf(x);
    float e = __expf(ax + ax);
    float t = 1.0f - 2.0f * __builtin_amdgcn_rcpf(e + 1.0f);
    return copysignf(t, x);
}

// ---------------------------------------------------------------------------
// Packed operand layouts (MFMA fragment-native):
//  B (weights): elem P = ((git*NT + nt)*64 + lane)*8 + e
//  A (acts):    elem = ((rb*(K/8) + (k>>3))*128) + (row&15)*8 + (k&7)
// ---------------------------------------------------------------------------
__device__ __forceinline__ void wpack_one(
    const float* __restrict__ src, bf16_t* __restrict__ dst,
    int P, int N, int NT, int Ksrc)
{
    int e = P & 7, lane = (P >> 3) & 63, idx = P >> 9;
    int nt = idx % NT, git = idx / NT;
    int n = nt * 16 + (lane & 15);
    int k = git * 32 + (lane >> 4) * 8 + e;
    dst[P] = (k < Ksrc) ? f2bf(src[(size_t)k * N + n]) : (bf16_t)0;
}

__global__ __launch_bounds__(256) void k_wpack(
    const float* __restrict__ W0, const float* __restrict__ W1, const float* __restrict__ W2,
    bf16_t* __restrict__ Wt0, bf16_t* __restrict__ Wt1, bf16_t* __restrict__ Wt2)
{
    const int m = blockIdx.y;
    const int P = blockIdx.x * 256 + threadIdx.x;
    if (m == 0)      { if (P < 319488) wpack_one(W0, Wt0, P, 96, 6, 3328); }
    else if (m == 1) { if (P < 147456) wpack_one(W1, Wt1, P, 96, 6, 1536); }
    else             { if (P < 204800) wpack_one(W2, Wt2, P, 128, 8, 1584); }
}

// ---------------------------------------------------------------------------
// K1: fused conv path, 2 samples/block.
// conv0: thread=(s,w,f-pair), f32 math, xr[28] via 7x ds_read_b128,
//        outputs -> LDS stage (lane-linear dword writes) + x0 (f16 pairs).
// flush stage0 -> packed pooled0 (uint4).
// conv1: thread=(w,fo), packed-f16; outputs -> stage (reused) -> uint4 flush.
// ---------------------------------------------------------------------------
__global__ __launch_bounds__(256) void k_conv_fused(
    const int* __restrict__ sp, const float* __restrict__ dn,
    const float* __restrict__ gen_table, const float* __restrict__ gen_W, const float* __restrict__ gen_b,
    const float* __restrict__ k0, const float* __restrict__ b0,
    const float* __restrict__ k1, const float* __restrict__ b1,
    bf16_t* __restrict__ pooled0, bf16_t* __restrict__ pooled1)
{
    __shared__ float embGt[2][32][28];             // [s][w][h], h=0..26, f32
    __shared__ unsigned int x0[2 * 13 * 32 * 4];   // f16-pair words [s][hp][w][q]
    __shared__ bf16_t stage[2][416][8];            // conv0 stage; reused for conv1
    __shared__ float k0s[56], k1s[448], b0s[8], b1s[8];
    __shared__ int ids[52];
    __shared__ float dloc[26];
    const int t = threadIdx.x;
    const int half = t >> 7, tt = t & 127;
    const int b = blockIdx.x * 2 + half;

    if (tt < 26) ids[half * 26 + tt] = sp[b * 26 + tt];
    if (tt >= 32 && tt < 45) dloc[half * 13 + tt - 32] = dn[b * 13 + (tt - 32)];
    if (t < 56) k0s[t] = k0[t];
    if (t >= 64 && t < 72) b0s[t - 64] = b0[t - 64];
    if (t >= 72 && t < 80) b1s[t - 72] = b1[t - 72];
    for (int i = t; i < 448; i += 256) k1s[i] = k1[i];
    __syncthreads();

    // gather gen rows (float4) -> transposed LDS; dense proj -> h=26
    for (int i = tt; i < 208; i += 128) {
        int s_ = i >> 3, d = (i & 7) * 4;
        float4 v = *(const float4*)(gen_table + (size_t)ids[half * 26 + s_] * 32 + d);
        embGt[half][d][s_] = v.x;
        embGt[half][d + 1][s_] = v.y;
        embGt[half][d + 2][s_] = v.z;
        embGt[half][d + 3][s_] = v.w;
    }
    if (tt < 32) {
        float a = gen_b[tt];
        #pragma unroll
        for (int k = 0; k < 13; k++) a += dloc[half * 13 + k] * gen_W[k * 32 + tt];
        embGt[half][tt][26] = a;
    }
    __syncthreads();

    // ---- conv0 + pool + tanh (27 -> 13), thread = (w, f-pair), own sample
    {
        const int w = tt >> 2, f0 = (tt & 3) * 2;
        const float* xp = &embGt[half][w][0];
        float xr[28];
        #pragma unroll
        for (int q = 0; q < 7; q++) {
            float4 v = *(const float4*)(xp + 4 * q);
            xr[4 * q] = v.x; xr[4 * q + 1] = v.y; xr[4 * q + 2] = v.z; xr[4 * q + 3] = v.w;
        }
        float k0r[7][2];
        #pragma unroll
        for (int tap = 0; tap < 7; tap++) {
            k0r[tap][0] = k0s[tap * 8 + f0];
            k0r[tap][1] = k0s[tap * 8 + f0 + 1];
        }
        const float b00 = b0s[f0], b01 = b0s[f0 + 1];
        #pragma unroll
        for (int hp = 0; hp < 13; hp++) {
            float p00 = b00, p01 = b01, p10 = b00, p11 = b01;
            #pragma unroll
            for (int tap = 0; tap < 7; tap++) {
                const int h0 = 2 * hp + tap - 3;
                if (h0 >= 0 && h0 < 27) {
                    p00 += xr[h0] * k0r[tap][0];
                    p01 += xr[h0] * k0r[tap][1];
                }
                const int h1 = 2 * hp + 1 + tap - 3;
                if (h1 >= 0 && h1 < 27) {
                    p10 += xr[h1] * k0r[tap][0];
                    p11 += xr[h1] * k0r[tap][1];
                }
            }
            float m0 = fast_tanh(fmaxf(p00, p10));
            float m1 = fast_tanh(fmaxf(p01, p11));
            unsigned int pk = (unsigned int)f2bf(m0) | ((unsigned int)f2bf(m1) << 16);
            *(unsigned int*)&stage[half][hp * 32 + w][f0] = pk;     // lane-linear
            U32H2 hx; hx.h = h2_t{(f16_t)m0, (f16_t)m1};
            x0[half * 1664 + hp * 128 + w * 4 + (tt & 3)] = hx.u;   // lane-linear
        }
    }
    __syncthreads();

    // flush conv0 stage -> packed pooled0 (832 uint4)
    #pragma unroll
    for (int i = t; i < 832; i += 256) {
        int s = (i >= 416) ? 1 : 0;
        int c = i - s * 416;
        int bb = blockIdx.x * 2 + s;
        uint4 v = *(const uint4*)&stage[s][c][0];
        *(uint4*)(pooled0 + (((size_t)(bb >> 4) * 416 + c) * 128 + (bb & 15) * 8)) = v;
    }

    // ---- conv1 + pool + tanh (13 -> 6), packed f16; accumulate in registers
    const int w1 = t >> 3, fo = t & 7;
    float m1out[2][6];
    {
        h2_t kh[7][4];
        #pragma unroll
        for (int tap = 0; tap < 7; tap++)
            #pragma unroll
            for (int q = 0; q < 4; q++)
                kh[tap][q] = h2_t{(f16_t)k1s[tap * 64 + (2 * q) * 8 + fo],
                                  (f16_t)k1s[tap * 64 + (2 * q + 1) * 8 + fo]};
        const f16_t bbh = (f16_t)b1s[fo];

        #pragma unroll
        for (int s = 0; s < 2; s++) {
            h2_t acc[12];
            #pragma unroll
            for (int r = 0; r < 12; r++) acc[r] = h2_t{bbh, (f16_t)0.f};
            #pragma unroll
            for (int hh = 0; hh < 13; hh++) {
                uint4 v = *(const uint4*)&x0[s * 1664 + hh * 128 + w1 * 4];
                U32H2 c0, c1, c2, c3;
                c0.u = v.x; c1.u = v.y; c2.u = v.z; c3.u = v.w;
                h2_t x2[4] = { c0.h, c1.h, c2.h, c3.h };
                #pragma unroll
                for (int tap = 0; tap < 7; tap++) {
                    const int r = hh + 3 - tap;
                    if (r >= 0 && r < 12) {
                        #pragma unroll
                        for (int q = 0; q < 4; q++) acc[r] += x2[q] * kh[tap][q];
                    }
                }
            }
            #pragma unroll
            for (int hp = 0; hp < 6; hp++) {
                float a0 = (float)acc[2 * hp][0] + (float)acc[2 * hp][1];
                float a1 = (float)acc[2 * hp + 1][0] + (float)acc[2 * hp + 1][1];
                m1out[s][hp] = fast_tanh(fmaxf(a0, a1));
            }
        }
    }
    __syncthreads();   // stage0 flush reads done -> safe to reuse stage
    #pragma unroll
    for (int s = 0; s < 2; s++)
        #pragma unroll
        for (int hp = 0; hp < 6; hp++)
            stage[s][hp * 32 + w1][fo] = f2bf(m1out[s][hp]);
    __syncthreads();
    // flush conv1 outputs: 384 uint4
    #pragma unroll
    for (int i = t; i < 384; i += 256) {
        int s = (i >= 192) ? 1 : 0;
        int c = i - s * 192;
        int bs = blockIdx.x * 2 + s;
        uint4 v = *(const uint4*)&stage[s][c][0];
        *(uint4*)(pooled1 + (((size_t)(bs >> 4) * 192 + c) * 128 + (bs & 15) * 8)) = v;
    }
}

// ---------------------------------------------------------------------------
// K2: both fc GEMMs, packed operands (unchanged).
// ---------------------------------------------------------------------------
__global__ __launch_bounds__(256) void k_fc_mfma(
    const bf16_t* __restrict__ A0, const bf16_t* __restrict__ Wt0, float* __restrict__ P0,
    const bf16_t* __restrict__ A1, const bf16_t* __restrict__ Wt1, float* __restrict__ P1)
{
    const int which = blockIdx.z;
    const bf16_t* A  = which ? A1 : A0;
    const bf16_t* Wt = which ? Wt1 : Wt0;
    float* P = (which ? P1 : P0) + (size_t)blockIdx.y * (BATCH * 96);
    const int K = which ? 1536 : 3328;
    const int iters = which ? 12 : 26;

    const int t = threadIdx.x, w = t >> 6, l = t & 63;
    const int lane15 = l & 15, quad = l >> 4;
    const int rb = blockIdx.x * 4 + w;
    const int kb = blockIdx.y * (K >> 2);

    const bf16_t* ap = A + ((size_t)rb * (K >> 3) + (kb >> 3) + quad) * 128 + lane15 * 8;
    const bf16_t* bp = Wt + (size_t)(kb >> 5) * 3072 + l * 8;
    f32x4 acc[6] = {};

    #pragma unroll 2
    for (int it = 0; it < iters; it++) {
        short8 a = *(const short8*)(ap + it * 512);
        #pragma unroll
        for (int nt = 0; nt < 6; nt++) {
            short8 bf = *(const short8*)(bp + it * 3072 + nt * 512);
            acc[nt] = __builtin_amdgcn_mfma_f32_16x16x32_bf16(a, bf, acc[nt], 0, 0, 0);
        }
    }
    const int baser = blockIdx.x * 64 + w * 16 + quad * 4;
    #pragma unroll
    for (int nt = 0; nt < 6; nt++)
        #pragma unroll
        for (int i = 0; i < 4; i++)
            P[(size_t)(baser + i) * 96 + nt * 16 + lane15] = acc[nt][i];
}

// ---------------------------------------------------------------------------
// K3: build h. One sample per wave; gram via 3 MFMAs; h row staged in LDS
// then flushed as uint4 chunks (packed A layout).
// ---------------------------------------------------------------------------
__global__ __launch_bounds__(256) void k_build_h(
    const int* __restrict__ sp, const float* __restrict__ dn,
    const float* __restrict__ cls_table, const float* __restrict__ cls_W, const float* __restrict__ cls_b,
    const float* __restrict__ p0, const float* __restrict__ fb0,
    const float* __restrict__ p1, const float* __restrict__ fb1,
    bf16_t* __restrict__ h)
{
    __shared__ bf16_t augs[4][33][40];
    __shared__ float grams[4][32][34];
    __shared__ bf16_t hrows[4][1600];
    const int t = threadIdx.x, wv = t >> 6, l = t & 63;
    const int b = blockIdx.x * 4 + wv;
    bf16_t (*aug)[40] = augs[wv];
    float (*gram)[34] = grams[wv];
    bf16_t* hrow = hrows[wv];

    const int myid = (l < 26) ? sp[b * 26 + l] : 0;

    for (int i = l; i < 416; i += 64) {
        int s_ = i >> 4, d = (i & 15) * 2;
        int id = __shfl(myid, s_);
        float2 v = *(const float2*)(cls_table + (size_t)id * 32 + d);
        unsigned int pk = (unsigned int)f2bf(v.x) | ((unsigned int)f2bf(v.y) << 16);
        *(unsigned int*)&aug[s_][d] = pk;
    }
    if (l < 32) {
        float a = cls_b[l];
        #pragma unroll
        for (int k = 0; k < 13; k++) a += dn[b * 13 + k] * cls_W[k * 32 + l];
        aug[26][l] = f2bf(a);
    }
    for (int i = l; i < 192; i += 64) {
        int n = 27 + (i >> 5), d = i & 31;
        float s;
        if (i < 96) {
            size_t o = (size_t)b * 96 + i;
            s = p0[o] + p0[o + 786432] + p0[o + 2 * 786432] + p0[o + 3 * 786432] + fb0[i];
        } else {
            int j = i - 96; size_t o = (size_t)b * 96 + j;
            s = p1[o] + p1[o + 786432] + p1[o + 2 * 786432] + p1[o + 3 * 786432] + fb1[j];
        }
        aug[n][d] = f2bf(fast_tanh(s));
    }

    const int m16 = l & 15, quad = l >> 4;
    short8 a0 = *(const short8*)&aug[m16][quad * 8];
    short8 a1 = *(const short8*)&aug[16 + m16][quad * 8];
    f32x4 c00 = {}, c01 = {}, c11 = {};
    c00 = __builtin_amdgcn_mfma_f32_16x16x32_bf16(a0, a0, c00, 0, 0, 0);
    c01 = __builtin_amdgcn_mfma_f32_16x16x32_bf16(a0, a1, c01, 0, 0, 0);
    c11 = __builtin_amdgcn_mfma_f32_16x16x32_bf16(a1, a1, c11, 0, 0, 0);
    #pragma unroll
    for (int i = 0; i < 4; i++) {
        gram[quad * 4 + i][m16] = c00[i];
        gram[quad * 4 + i][16 + m16] = c01[i];
        gram[16 + quad * 4 + i][16 + m16] = c11[i];
    }
    if (l < 32) {
        float s = 0.f;
        #pragma unroll
        for (int kk = 0; kk < 16; kk++) {
            unsigned int x = *(const unsigned int*)&aug[l][2 * kk];
            unsigned int y = *(const unsigned int*)&aug[32][2 * kk];
            s += bf2f((bf16_t)(x & 0xFFFFu)) * bf2f((bf16_t)(y & 0xFFFFu));
            s += bf2f((bf16_t)(x >> 16)) * bf2f((bf16_t)(y >> 16));
        }
        gram[l][32] = s;
    }

    for (int idx = l; idx < 528; idx += 64)
        *(unsigned int*)&hrow[528 + 2 * idx] = *(const unsigned int*)&aug[idx >> 4][(idx & 15) * 2];
    if (l < 8) *(unsigned int*)&hrow[1584 + 2 * l] = 0u;
    for (int pp = l; pp < 264; pp += 64) {
        int p = 2 * pp;
        int i = (int)((65.0f - sqrtf(4225.0f - 8.0f * (float)p)) * 0.5f);
        int st = (i * (65 - i)) >> 1;
        if (st > p) { i--; st = (i * (65 - i)) >> 1; }
        else { int st2 = ((i + 1) * (64 - i)) >> 1; if (st2 <= p) { i++; st = st2; } }
        int j = i + 1 + (p - st);
        float s0, s1;
        if (j < 32) { s0 = gram[i][j]; s1 = gram[i][j + 1]; }
        else        { s0 = gram[i][32]; s1 = gram[i + 1][i + 2]; }
        *(unsigned int*)&hrow[p] = (unsigned int)f2bf(s0) | ((unsigned int)f2bf(s1) << 16);
    }
    bf16_t* hbp = h + ((size_t)(b >> 4) * 200) * 128 + (b & 15) * 8;
    for (int c = l; c < 200; c += 64) {
        uint4 v = *(const uint4*)&hrow[c * 8];
        *(uint4*)(hbp + (size_t)c * 128) = v;
    }
}

// ---------------------------------------------------------------------------
// K4: MLP, packed operands (unchanged).
// ---------------------------------------------------------------------------
__global__ __launch_bounds__(256) void k_mlp_mfma(
    const bf16_t* __restrict__ h, const bf16_t* __restrict__ Wt2,
    const float* __restrict__ b1, const float* __restrict__ gamma,
    const float* __restrict__ beta, const float* __restrict__ mean,
    const float* __restrict__ var, const float* __restrict__ outW,
    const float* __restrict__ outb, float* __restrict__ out)
{
    __shared__ float lds[2 * 16 * 65];
    __shared__ float red2[32];
    const int t = threadIdx.x, w = t >> 6, l = t & 63;
    const int lane15 = l & 15, quad = l >> 4;
    const int nhalf = w & 1, khalf = w >> 1;

    const bf16_t* ap = h + ((size_t)blockIdx.x * 200 + khalf * 100 + quad) * 128 + lane15 * 8;
    const bf16_t* bp = Wt2 + ((size_t)khalf * 25 * 8 + nhalf * 4) * 512 + l * 8;
    f32x4 acc[4] = {};

    #pragma unroll 2
    for (int it = 0; it < 25; it++) {
        short8 a = *(const short8*)(ap + it * 512);
        #pragma unroll
        for (int nt = 0; nt < 4; nt++) {
            short8 bf = *(const short8*)(bp + it * 4096 + nt * 512);
            acc[nt] = __builtin_amdgcn_mfma_f32_16x16x32_bf16(a, bf, acc[nt], 0, 0, 0);
        }
    }

    if (khalf == 1) {
        #pragma unroll
        for (int nt = 0; nt < 4; nt++)
            #pragma unroll
            for (int i = 0; i < 4; i++)
                lds[nhalf * 1040 + (quad * 4 + i) * 65 + nt * 16 + lane15] = acc[nt][i];
    }
    __syncthreads();
    if (khalf == 0) {
        float pl[4] = { 0.f, 0.f, 0.f, 0.f };
        #pragma unroll
        for (int nt = 0; nt < 4; nt++) {
            int c = nhalf * 64 + nt * 16 + lane15;
            float sc = gamma[c] * rsqrtf(var[c] + 1e-3f);
            float sh = beta[c] - mean[c] * sc;
            float ow = outW[c], bb = b1[c];
            #pragma unroll
            for (int i = 0; i < 4; i++) {
                float v = acc[nt][i] + lds[nhalf * 1040 + (quad * 4 + i) * 65 + nt * 16 + lane15] + bb;
                v = fmaxf(v, 0.f);
                pl[i] += (v * sc + sh) * ow;
            }
        }
        #pragma unroll
        for (int m = 1; m < 16; m <<= 1)
            #pragma unroll
            for (int i = 0; i < 4; i++) pl[i] += __shfl_xor(pl[i], m);
        if (lane15 == 0) {
            #pragma unroll
            for (int i = 0; i < 4; i++) red2[(quad * 4 + i) * 2 + nhalf] = pl[i];
        }
    }
    __syncthreads();
    if (t < 16) {
        float s = red2[t * 2] + red2[t * 2 + 1] + outb[0];
        out[blockIdx.x * 16 + t] = 1.f / (1.f + __expf(-s));
    }
}

// ---------------------------------------------------------------------------
extern "C" void kernel_launch(void* const* d_in, const int* in_sizes, int n_in,
                              void* d_out, int out_size, void* d_ws, size_t ws_size,
                              hipStream_t stream) {
    const int*   sp       = (const int*)d_in[0];
    const float* dn       = (const float*)d_in[1];
    const float* gen_tab  = (const float*)d_in[2];
    const float* gen_W    = (const float*)d_in[3];
    const float* gen_b    = (const float*)d_in[4];
    const float* cls_tab  = (const float*)d_in[5];
    const float* cls_W    = (const float*)d_in[6];
    const float* cls_b    = (const float*)d_in[7];
    const float* conv_k0  = (const float*)d_in[8];
    const float* conv_b0  = (const float*)d_in[9];
    const float* fc_W0    = (const float*)d_in[10];
    const float* fc_b0    = (const float*)d_in[11];
    const float* conv_k1  = (const float*)d_in[12];
    const float* conv_b1  = (const float*)d_in[13];
    const float* fc_W1    = (const float*)d_in[14];
    const float* fc_b1    = (const float*)d_in[15];
    const float* mlp_W1   = (const float*)d_in[16];
    const float* mlp_b1   = (const float*)d_in[17];
    const float* bn_gamma = (const float*)d_in[18];
    const float* bn_beta  = (const float*)d_in[19];
    const float* bn_mean  = (const float*)d_in[20];
    const float* bn_var   = (const float*)d_in[21];
    const float* out_W    = (const float*)d_in[22];
    const float* out_b    = (const float*)d_in[23];
    float* out = (float*)d_out;

    char* ws = (char*)d_ws;
    bf16_t* pooled0 = (bf16_t*)(ws + 0);
    bf16_t* pooled1 = (bf16_t*)(ws + 54525952ULL);
    float*  p0      = (float*)(ws + 79691776ULL);
    float*  p1      = (float*)(ws + 92274688ULL);
    bf16_t* Wt0     = (bf16_t*)(ws + 104857600ULL);
    bf16_t* Wt1     = (bf16_t*)(ws + 105496576ULL);
    bf16_t* Wt2     = (bf16_t*)(ws + 105791488ULL);
    bf16_t* h       = (bf16_t*)(ws + 0);   // aliases pooled0 (consumed by fc before build_h)

    k_wpack<<<dim3(1248, 3), 256, 0, stream>>>(fc_W0, fc_W1, mlp_W1, Wt0, Wt1, Wt2);
    k_conv_fused<<<BATCH / 2, 256, 0, stream>>>(sp, dn, gen_tab, gen_W, gen_b,
                                                conv_k0, conv_b0, conv_k1, conv_b1,
                                                pooled0, pooled1);
    k_fc_mfma<<<dim3(BATCH / 64, 4, 2), 256, 0, stream>>>(pooled0, Wt0, p0, pooled1, Wt1, p1);
    k_build_h<<<BATCH / 4, 256, 0, stream>>>(sp, dn, cls_tab, cls_W, cls_b,
                                             p0, fc_b0, p1, fc_b1, h);
    k_mlp_mfma<<<BATCH / 16, 256, 0, stream>>>(h, Wt2, mlp_b1, bn_gamma, bn_beta,
                                               bn_mean, bn_var, out_W, out_b, out);
}

// Round 10
// 235.628 us; speedup vs baseline: 1.0401x; 1.0401x over previous
//
#include <hip/hip_runtime.h>
#include <hip/hip_bf16.h>
#include <math.h>

#define BATCH 8192

typedef _Float16 f16_t;
typedef __attribute__((ext_vector_type(2))) _Float16 h2_t;
typedef __attribute__((ext_vector_type(8))) _Float16 half8;
typedef __attribute__((ext_vector_type(4))) float f32x4;

union U32H2 { unsigned int u; h2_t h; };

// tanh(x) = sign(x) * (1 - 2/(exp(2|x|)+1)); err ~1e-6
__device__ __forceinline__ float fast_tanh(float x) {
    float ax = fabsf(x);
    float e = __expf(ax + ax);
    float t = 1.0f - 2.0f * __builtin_amdgcn_rcpf(e + 1.0f);
    return copysignf(t, x);
}

// ---------------------------------------------------------------------------
// Packed operand layouts (MFMA fragment-native), all f16:
//  B (weights): elem P = ((git*NT + nt)*64 + lane)*8 + e
//               holds W[n = nt*16 + (lane&15)][k = git*32 + (lane>>4)*8 + e]
//  A (acts):    elem = ((rb*(K/8) + (k>>3))*128) + (row&15)*8 + (k&7)
// ---------------------------------------------------------------------------
__device__ __forceinline__ void wpack_one(
    const float* __restrict__ src, f16_t* __restrict__ dst,
    int P, int N, int NT, int Ksrc)
{
    int e = P & 7, lane = (P >> 3) & 63, idx = P >> 9;
    int nt = idx % NT, git = idx / NT;
    int n = nt * 16 + (lane & 15);
    int k = git * 32 + (lane >> 4) * 8 + e;
    dst[P] = (k < Ksrc) ? (f16_t)src[(size_t)k * N + n] : (f16_t)0.f;
}

__global__ __launch_bounds__(256) void k_wpack(
    const float* __restrict__ W0, const float* __restrict__ W1, const float* __restrict__ W2,
    f16_t* __restrict__ Wt0, f16_t* __restrict__ Wt1, f16_t* __restrict__ Wt2)
{
    const int m = blockIdx.y;
    const int P = blockIdx.x * 256 + threadIdx.x;
    if (m == 0)      { if (P < 319488) wpack_one(W0, Wt0, P, 96, 6, 3328); }
    else if (m == 1) { if (P < 147456) wpack_one(W1, Wt1, P, 96, 6, 1536); }
    else             { if (P < 204800) wpack_one(W2, Wt2, P, 128, 8, 1584); }
}

// ---------------------------------------------------------------------------
// K1: fused conv path, 2 samples/block, all-f16 outputs.
// conv0: thread=(s,w,f-pair), f32 math from LDS-transposed embGt (b128 reads),
//        single output write into x0 (f16 pairs, lane-linear).
// flush pooled0 straight from x0; conv1 packed-f16 -> embGt-space stage ->
// uint4 flush.
// ---------------------------------------------------------------------------
__global__ __launch_bounds__(256) void k_conv_fused(
    const int* __restrict__ sp, const float* __restrict__ dn,
    const float* __restrict__ gen_table, const float* __restrict__ gen_W, const float* __restrict__ gen_b,
    const float* __restrict__ k0, const float* __restrict__ b0,
    const float* __restrict__ k1, const float* __restrict__ b1,
    f16_t* __restrict__ pooled0, f16_t* __restrict__ pooled1)
{
    __shared__ float embGt[2][32][28];             // [s][w][h]; reused as conv1 stage
    __shared__ unsigned int x0[2 * 1664];          // f16-pair words [s][hp*32+w][q]
    __shared__ float k0s[56], k1s[448], b0s[8], b1s[8];
    __shared__ int ids[52];
    __shared__ float dloc[26];
    const int t = threadIdx.x;
    const int half = t >> 7, tt = t & 127;
    const int b = blockIdx.x * 2 + half;

    if (tt < 26) ids[half * 26 + tt] = sp[b * 26 + tt];
    if (tt >= 32 && tt < 45) dloc[half * 13 + tt - 32] = dn[b * 13 + (tt - 32)];
    if (t < 56) k0s[t] = k0[t];
    if (t >= 64 && t < 72) b0s[t - 64] = b0[t - 64];
    if (t >= 72 && t < 80) b1s[t - 72] = b1[t - 72];
    for (int i = t; i < 448; i += 256) k1s[i] = k1[i];
    __syncthreads();

    // gather gen rows (float4) -> transposed LDS; dense proj -> h=26
    for (int i = tt; i < 208; i += 128) {
        int s_ = i >> 3, d = (i & 7) * 4;
        float4 v = *(const float4*)(gen_table + (size_t)ids[half * 26 + s_] * 32 + d);
        embGt[half][d][s_] = v.x;
        embGt[half][d + 1][s_] = v.y;
        embGt[half][d + 2][s_] = v.z;
        embGt[half][d + 3][s_] = v.w;
    }
    if (tt < 32) {
        float a = gen_b[tt];
        #pragma unroll
        for (int k = 0; k < 13; k++) a += dloc[half * 13 + k] * gen_W[k * 32 + tt];
        embGt[half][tt][26] = a;
    }
    __syncthreads();

    // ---- conv0 + pool + tanh (27 -> 13), thread = (w, f-pair), own sample
    {
        const int w = tt >> 2, f0 = (tt & 3) * 2;
        const float* xp = &embGt[half][w][0];
        float xr[28];
        #pragma unroll
        for (int q = 0; q < 7; q++) {
            float4 v = *(const float4*)(xp + 4 * q);
            xr[4 * q] = v.x; xr[4 * q + 1] = v.y; xr[4 * q + 2] = v.z; xr[4 * q + 3] = v.w;
        }
        float k0r[7][2];
        #pragma unroll
        for (int tap = 0; tap < 7; tap++) {
            k0r[tap][0] = k0s[tap * 8 + f0];
            k0r[tap][1] = k0s[tap * 8 + f0 + 1];
        }
        const float b00 = b0s[f0], b01 = b0s[f0 + 1];
        unsigned int xloc[13];
        #pragma unroll
        for (int hp = 0; hp < 13; hp++) {
            float p00 = b00, p01 = b01, p10 = b00, p11 = b01;
            #pragma unroll
            for (int tap = 0; tap < 7; tap++) {
                const int h0 = 2 * hp + tap - 3;
                if (h0 >= 0 && h0 < 27) {
                    p00 += xr[h0] * k0r[tap][0];
                    p01 += xr[h0] * k0r[tap][1];
                }
                const int h1 = 2 * hp + 1 + tap - 3;
                if (h1 >= 0 && h1 < 27) {
                    p10 += xr[h1] * k0r[tap][0];
                    p11 += xr[h1] * k0r[tap][1];
                }
            }
            float m0 = fast_tanh(fmaxf(p00, p10));
            float m1 = fast_tanh(fmaxf(p01, p11));
            U32H2 hx; hx.h = h2_t{(f16_t)m0, (f16_t)m1};
            xloc[hp] = hx.u;
        }
        #pragma unroll
        for (int hp = 0; hp < 13; hp++)
            x0[half * 1664 + hp * 128 + tt] = xloc[hp];   // lane-linear
    }
    __syncthreads();

    // flush pooled0 straight from x0 (832 uint4)
    #pragma unroll
    for (int i = t; i < 832; i += 256) {
        int s = (i >= 416) ? 1 : 0;
        int c = i - s * 416;
        int bb = blockIdx.x * 2 + s;
        uint4 v = *(const uint4*)&x0[s * 1664 + c * 4];
        *(uint4*)(pooled0 + (((size_t)(bb >> 4) * 416 + c) * 128 + (bb & 15) * 8)) = v;
    }

    // ---- conv1 + pool + tanh (13 -> 6), packed f16; accumulate in registers
    const int w1 = t >> 3, fo = t & 7;
    float m1out[2][6];
    {
        h2_t kh[7][4];
        #pragma unroll
        for (int tap = 0; tap < 7; tap++)
            #pragma unroll
            for (int q = 0; q < 4; q++)
                kh[tap][q] = h2_t{(f16_t)k1s[tap * 64 + (2 * q) * 8 + fo],
                                  (f16_t)k1s[tap * 64 + (2 * q + 1) * 8 + fo]};
        const f16_t bbh = (f16_t)b1s[fo];

        #pragma unroll
        for (int s = 0; s < 2; s++) {
            h2_t acc[12];
            #pragma unroll
            for (int r = 0; r < 12; r++) acc[r] = h2_t{bbh, (f16_t)0.f};
            #pragma unroll
            for (int hh = 0; hh < 13; hh++) {
                uint4 v = *(const uint4*)&x0[s * 1664 + hh * 128 + w1 * 4];
                U32H2 c0, c1, c2, c3;
                c0.u = v.x; c1.u = v.y; c2.u = v.z; c3.u = v.w;
                h2_t x2[4] = { c0.h, c1.h, c2.h, c3.h };
                #pragma unroll
                for (int tap = 0; tap < 7; tap++) {
                    const int r = hh + 3 - tap;
                    if (r >= 0 && r < 12) {
                        #pragma unroll
                        for (int q = 0; q < 4; q++) acc[r] += x2[q] * kh[tap][q];
                    }
                }
            }
            #pragma unroll
            for (int hp = 0; hp < 6; hp++) {
                float a0 = (float)acc[2 * hp][0] + (float)acc[2 * hp][1];
                float a1 = (float)acc[2 * hp + 1][0] + (float)acc[2 * hp + 1][1];
                m1out[s][hp] = fast_tanh(fmaxf(a0, a1));
            }
        }
    }
    __syncthreads();   // embGt reads (conv0) + x0 flush done -> reuse embGt as stage
    f16_t* stg = (f16_t*)&embGt[0][0][0];   // [s][c][fo], c=hp*32+w1 (0..191)
    #pragma unroll
    for (int s = 0; s < 2; s++)
        #pragma unroll
        for (int hp = 0; hp < 6; hp++)
            stg[(s * 192 + hp * 32 + w1) * 8 + fo] = (f16_t)m1out[s][hp];
    __syncthreads();
    // flush conv1 outputs: 384 uint4
    #pragma unroll
    for (int i = t; i < 384; i += 256) {
        int s = (i >= 192) ? 1 : 0;
        int c = i - s * 192;
        int bs = blockIdx.x * 2 + s;
        uint4 v = *(const uint4*)&stg[(s * 192 + c) * 8];
        *(uint4*)(pooled1 + (((size_t)(bs >> 4) * 192 + c) * 128 + (bs & 15) * 8)) = v;
    }
}

// ---------------------------------------------------------------------------
// K2: both fc GEMMs, packed f16 operands.
// ---------------------------------------------------------------------------
__global__ __launch_bounds__(256) void k_fc_mfma(
    const f16_t* __restrict__ A0, const f16_t* __restrict__ Wt0, float* __restrict__ P0,
    const f16_t* __restrict__ A1, const f16_t* __restrict__ Wt1, float* __restrict__ P1)
{
    const int which = blockIdx.z;
    const f16_t* A  = which ? A1 : A0;
    const f16_t* Wt = which ? Wt1 : Wt0;
    float* P = (which ? P1 : P0) + (size_t)blockIdx.y * (BATCH * 96);
    const int K = which ? 1536 : 3328;
    const int iters = which ? 12 : 26;

    const int t = threadIdx.x, w = t >> 6, l = t & 63;
    const int lane15 = l & 15, quad = l >> 4;
    const int rb = blockIdx.x * 4 + w;
    const int kb = blockIdx.y * (K >> 2);

    const f16_t* ap = A + ((size_t)rb * (K >> 3) + (kb >> 3) + quad) * 128 + lane15 * 8;
    const f16_t* bp = Wt + (size_t)(kb >> 5) * 3072 + l * 8;
    f32x4 acc[6] = {};

    #pragma unroll 2
    for (int it = 0; it < iters; it++) {
        half8 a = *(const half8*)(ap + it * 512);
        #pragma unroll
        for (int nt = 0; nt < 6; nt++) {
            half8 bf = *(const half8*)(bp + it * 3072 + nt * 512);
            acc[nt] = __builtin_amdgcn_mfma_f32_16x16x32_f16(a, bf, acc[nt], 0, 0, 0);
        }
    }
    const int baser = blockIdx.x * 64 + w * 16 + quad * 4;
    #pragma unroll
    for (int nt = 0; nt < 6; nt++)
        #pragma unroll
        for (int i = 0; i < 4; i++)
            P[(size_t)(baser + i) * 96 + nt * 16 + lane15] = acc[nt][i];
}

// ---------------------------------------------------------------------------
// K3: build h (f16). One sample per wave; gram via 3 f16 MFMAs; h row staged
// in LDS then flushed as uint4 chunks (packed A layout).
// ---------------------------------------------------------------------------
__global__ __launch_bounds__(256) void k_build_h(
    const int* __restrict__ sp, const float* __restrict__ dn,
    const float* __restrict__ cls_table, const float* __restrict__ cls_W, const float* __restrict__ cls_b,
    const float* __restrict__ p0, const float* __restrict__ fb0,
    const float* __restrict__ p1, const float* __restrict__ fb1,
    f16_t* __restrict__ h)
{
    __shared__ f16_t augs[4][33][40];
    __shared__ float grams[4][32][34];
    __shared__ f16_t hrows[4][1600];
    const int t = threadIdx.x, wv = t >> 6, l = t & 63;
    const int b = blockIdx.x * 4 + wv;
    f16_t (*aug)[40] = augs[wv];
    float (*gram)[34] = grams[wv];
    f16_t* hrow = hrows[wv];

    const int myid = (l < 26) ? sp[b * 26 + l] : 0;

    for (int i = l; i < 416; i += 64) {
        int s_ = i >> 4, d = (i & 15) * 2;
        int id = __shfl(myid, s_);
        float2 v = *(const float2*)(cls_table + (size_t)id * 32 + d);
        U32H2 hx; hx.h = h2_t{(f16_t)v.x, (f16_t)v.y};
        *(unsigned int*)&aug[s_][d] = hx.u;
    }
    if (l < 32) {
        float a = cls_b[l];
        #pragma unroll
        for (int k = 0; k < 13; k++) a += dn[b * 13 + k] * cls_W[k * 32 + l];
        aug[26][l] = (f16_t)a;
    }
    for (int i = l; i < 192; i += 64) {
        int n = 27 + (i >> 5), d = i & 31;
        float s;
        if (i < 96) {
            size_t o = (size_t)b * 96 + i;
            s = p0[o] + p0[o + 786432] + p0[o + 2 * 786432] + p0[o + 3 * 786432] + fb0[i];
        } else {
            int j = i - 96; size_t o = (size_t)b * 96 + j;
            s = p1[o] + p1[o + 786432] + p1[o + 2 * 786432] + p1[o + 3 * 786432] + fb1[j];
        }
        aug[n][d] = (f16_t)fast_tanh(s);
    }

    const int m16 = l & 15, quad = l >> 4;
    half8 a0 = *(const half8*)&aug[m16][quad * 8];
    half8 a1 = *(const half8*)&aug[16 + m16][quad * 8];
    f32x4 c00 = {}, c01 = {}, c11 = {};
    c00 = __builtin_amdgcn_mfma_f32_16x16x32_f16(a0, a0, c00, 0, 0, 0);
    c01 = __builtin_amdgcn_mfma_f32_16x16x32_f16(a0, a1, c01, 0, 0, 0);
    c11 = __builtin_amdgcn_mfma_f32_16x16x32_f16(a1, a1, c11, 0, 0, 0);
    #pragma unroll
    for (int i = 0; i < 4; i++) {
        gram[quad * 4 + i][m16] = c00[i];
        gram[quad * 4 + i][16 + m16] = c01[i];
        gram[16 + quad * 4 + i][16 + m16] = c11[i];
    }
    if (l < 32) {
        float s = 0.f;
        #pragma unroll
        for (int kk = 0; kk < 16; kk++) {
            U32H2 x, y;
            x.u = *(const unsigned int*)&aug[l][2 * kk];
            y.u = *(const unsigned int*)&aug[32][2 * kk];
            s += (float)x.h[0] * (float)y.h[0];
            s += (float)x.h[1] * (float)y.h[1];
        }
        gram[l][32] = s;
    }

    for (int idx = l; idx < 528; idx += 64)
        *(unsigned int*)&hrow[528 + 2 * idx] = *(const unsigned int*)&aug[idx >> 4][(idx & 15) * 2];
    if (l < 8) *(unsigned int*)&hrow[1584 + 2 * l] = 0u;
    for (int pp = l; pp < 264; pp += 64) {
        int p = 2 * pp;
        int i = (int)((65.0f - sqrtf(4225.0f - 8.0f * (float)p)) * 0.5f);
        int st = (i * (65 - i)) >> 1;
        if (st > p) { i--; st = (i * (65 - i)) >> 1; }
        else { int st2 = ((i + 1) * (64 - i)) >> 1; if (st2 <= p) { i++; st = st2; } }
        int j = i + 1 + (p - st);
        float s0, s1;
        if (j < 32) { s0 = gram[i][j]; s1 = gram[i][j + 1]; }
        else        { s0 = gram[i][32]; s1 = gram[i + 1][i + 2]; }
        U32H2 hx; hx.h = h2_t{(f16_t)s0, (f16_t)s1};
        *(unsigned int*)&hrow[p] = hx.u;
    }
    f16_t* hbp = h + ((size_t)(b >> 4) * 200) * 128 + (b & 15) * 8;
    for (int c = l; c < 200; c += 64) {
        uint4 v = *(const uint4*)&hrow[c * 8];
        *(uint4*)(hbp + (size_t)c * 128) = v;
    }
}

// ---------------------------------------------------------------------------
// K4: MLP, packed f16 operands.
// ---------------------------------------------------------------------------
__global__ __launch_bounds__(256) void k_mlp_mfma(
    const f16_t* __restrict__ h, const f16_t* __restrict__ Wt2,
    const float* __restrict__ b1, const float* __restrict__ gamma,
    const float* __restrict__ beta, const float* __restrict__ mean,
    const float* __restrict__ var, const float* __restrict__ outW,
    const float* __restrict__ outb, float* __restrict__ out)
{
    __shared__ float lds[2 * 16 * 65];
    __shared__ float red2[32];
    const int t = threadIdx.x, w = t >> 6, l = t & 63;
    const int lane15 = l & 15, quad = l >> 4;
    const int nhalf = w & 1, khalf = w >> 1;

    const f16_t* ap = h + ((size_t)blockIdx.x * 200 + khalf * 100 + quad) * 128 + lane15 * 8;
    const f16_t* bp = Wt2 + ((size_t)khalf * 25 * 8 + nhalf * 4) * 512 + l * 8;
    f32x4 acc[4] = {};

    #pragma unroll 2
    for (int it = 0; it < 25; it++) {
        half8 a = *(const half8*)(ap + it * 512);
        #pragma unroll
        for (int nt = 0; nt < 4; nt++) {
            half8 bf = *(const half8*)(bp + it * 4096 + nt * 512);
            acc[nt] = __builtin_amdgcn_mfma_f32_16x16x32_f16(a, bf, acc[nt], 0, 0, 0);
        }
    }

    if (khalf == 1) {
        #pragma unroll
        for (int nt = 0; nt < 4; nt++)
            #pragma unroll
            for (int i = 0; i < 4; i++)
                lds[nhalf * 1040 + (quad * 4 + i) * 65 + nt * 16 + lane15] = acc[nt][i];
    }
    __syncthreads();
    if (khalf == 0) {
        float pl[4] = { 0.f, 0.f, 0.f, 0.f };
        #pragma unroll
        for (int nt = 0; nt < 4; nt++) {
            int c = nhalf * 64 + nt * 16 + lane15;
            float sc = gamma[c] * rsqrtf(var[c] + 1e-3f);
            float sh = beta[c] - mean[c] * sc;
            float ow = outW[c], bb = b1[c];
            #pragma unroll
            for (int i = 0; i < 4; i++) {
                float v = acc[nt][i] + lds[nhalf * 1040 + (quad * 4 + i) * 65 + nt * 16 + lane15] + bb;
                v = fmaxf(v, 0.f);
                pl[i] += (v * sc + sh) * ow;
            }
        }
        #pragma unroll
        for (int m = 1; m < 16; m <<= 1)
            #pragma unroll
            for (int i = 0; i < 4; i++) pl[i] += __shfl_xor(pl[i], m);
        if (lane15 == 0) {
            #pragma unroll
            for (int i = 0; i < 4; i++) red2[(quad * 4 + i) * 2 + nhalf] = pl[i];
        }
    }
    __syncthreads();
    if (t < 16) {
        float s = red2[t * 2] + red2[t * 2 + 1] + outb[0];
        out[blockIdx.x * 16 + t] = 1.f / (1.f + __expf(-s));
    }
}

// ---------------------------------------------------------------------------
extern "C" void kernel_launch(void* const* d_in, const int* in_sizes, int n_in,
                              void* d_out, int out_size, void* d_ws, size_t ws_size,
                              hipStream_t stream) {
    const int*   sp       = (const int*)d_in[0];
    const float* dn       = (const float*)d_in[1];
    const float* gen_tab  = (const float*)d_in[2];
    const float* gen_W    = (const float*)d_in[3];
    const float* gen_b    = (const float*)d_in[4];
    const float* cls_tab  = (const float*)d_in[5];
    const float* cls_W    = (const float*)d_in[6];
    const float* cls_b    = (const float*)d_in[7];
    const float* conv_k0  = (const float*)d_in[8];
    const float* conv_b0  = (const float*)d_in[9];
    const float* fc_W0    = (const float*)d_in[10];
    const float* fc_b0    = (const float*)d_in[11];
    const float* conv_k1  = (const float*)d_in[12];
    const float* conv_b1  = (const float*)d_in[13];
    const float* fc_W1    = (const float*)d_in[14];
    const float* fc_b1    = (const float*)d_in[15];
    const float* mlp_W1   = (const float*)d_in[16];
    const float* mlp_b1   = (const float*)d_in[17];
    const float* bn_gamma = (const float*)d_in[18];
    const float* bn_beta  = (const float*)d_in[19];
    const float* bn_mean  = (const float*)d_in[20];
    const float* bn_var   = (const float*)d_in[21];
    const float* out_W    = (const float*)d_in[22];
    const float* out_b    = (const float*)d_in[23];
    float* out = (float*)d_out;

    char* ws = (char*)d_ws;
    f16_t* pooled0 = (f16_t*)(ws + 0);
    f16_t* pooled1 = (f16_t*)(ws + 54525952ULL);
    float* p0      = (float*)(ws + 79691776ULL);
    float* p1      = (float*)(ws + 92274688ULL);
    f16_t* Wt0     = (f16_t*)(ws + 104857600ULL);
    f16_t* Wt1     = (f16_t*)(ws + 105496576ULL);
    f16_t* Wt2     = (f16_t*)(ws + 105791488ULL);
    f16_t* h       = (f16_t*)(ws + 0);   // aliases pooled0 (consumed by fc before build_h)

    k_wpack<<<dim3(1248, 3), 256, 0, stream>>>(fc_W0, fc_W1, mlp_W1, Wt0, Wt1, Wt2);
    k_conv_fused<<<BATCH / 2, 256, 0, stream>>>(sp, dn, gen_tab, gen_W, gen_b,
                                                conv_k0, conv_b0, conv_k1, conv_b1,
                                                pooled0, pooled1);
    k_fc_mfma<<<dim3(BATCH / 64, 4, 2), 256, 0, stream>>>(pooled0, Wt0, p0, pooled1, Wt1, p1);
    k_build_h<<<BATCH / 4, 256, 0, stream>>>(sp, dn, cls_tab, cls_W, cls_b,
                                             p0, fc_b0, p1, fc_b1, h);
    k_mlp_mfma<<<BATCH / 16, 256, 0, stream>>>(h, Wt2, mlp_b1, bn_gamma, bn_beta,
                                               bn_mean, bn_var, out_W, out_b, out);
}